// Round 6
// baseline (309.485 us; speedup 1.0000x reference)
//
#include <hip/hip_runtime.h>
#include <math.h>

#define N_NODES 50000
#define N_EDGES 800000
#define NFEAT 256
#define NHID 64
#define NCLASS 40
#define NPAD_ROWS 50048   // gemm2 reads h in 64-row blocks: 782*64
#define NPB 16            // nodes per bucket
#define NB  3125          // 50000 / 16
#define NSEG 7            // segments of 131072 edges (e >> 17), max s = 6
#define SEGSH 17

typedef __attribute__((ext_vector_type(8))) short bf16x8;
typedef __attribute__((ext_vector_type(4))) float f32x4;

__device__ __forceinline__ ushort f2bf(float f) {
    unsigned u = __float_as_uint(f);
    u += 0x7FFF + ((u >> 16) & 1);          // round-to-nearest-even
    return (ushort)(u >> 16);
}
__device__ __forceinline__ float bf2f(ushort us) {
    return __uint_as_float(((unsigned)us) << 16);
}

// ---------------- bucket CSR build (flat, segmented counters) ----------------

__global__ void k_bhist(const int* __restrict__ edst, int* __restrict__ bcnt) {
    int e = blockIdx.x * 256 + threadIdx.x;
    if (e < N_EDGES) {
        int s = e >> SEGSH;
        atomicAdd(&bcnt[s * NB + (edst[e] >> 4)], 1);
    }
}

// Wave-aggregated allocation of disjoint (s,b) ranges; global order irrelevant.
__global__ void k_bscan(const int* __restrict__ bcnt, int* __restrict__ bstart,
                        int* __restrict__ bcur, int* __restrict__ cursor) {
    int i = blockIdx.x * 256 + threadIdx.x;
    int lane = threadIdx.x & 63;
    int c = (i < NSEG * NB) ? bcnt[i] : 0;
    int incl = c;
    #pragma unroll
    for (int off = 1; off < 64; off <<= 1) {
        int n = __shfl_up(incl, off);
        if (lane >= off) incl += n;
    }
    int total = __shfl(incl, 63);
    int base = 0;
    if (lane == 0) base = atomicAdd(cursor, total);
    base = __shfl(base, 0);
    if (i < NSEG * NB) {
        int s = base + incl - c;
        bstart[i] = s;
        bcur[i] = s;
    }
}

// Flat scatter: claim slot in (segment,bucket) range, store packed payload.
__global__ void k_bin(const int* __restrict__ esrc, const int* __restrict__ edst,
                      const float* __restrict__ ewt, int* __restrict__ bcur,
                      int2* __restrict__ binned) {
    int e = blockIdx.x * 256 + threadIdx.x;
    if (e < N_EDGES) {
        int d = edst[e];
        int s = e >> SEGSH;
        int pos = atomicAdd(&bcur[s * NB + (d >> 4)], 1);
        binned[pos] = make_int2(esrc[e] | ((d & 15) << 16), __float_as_int(ewt[e]));
    }
}

// ---------------- prep: W1,W2 -> bf16 fragment-ordered tables ----------------

__global__ void k_prep(const float* __restrict__ W1, const float* __restrict__ W2,
                       ushort* __restrict__ W1f, ushort* __restrict__ W2f) {
    int idx = blockIdx.x * 256 + threadIdx.x;
    if (idx < 2048) {                        // 4 ct * 8 ks * 64 lanes
        int lane = idx & 63, ctks = idx >> 6;
        int ks = ctks & 7, ct = ctks >> 3;
        int col = ct * 16 + (lane & 15);
        int r0 = ks * 32 + (lane >> 4) * 8;
        bf16x8 frag;
        #pragma unroll
        for (int j = 0; j < 8; ++j) frag[j] = (short)f2bf(W1[(r0 + j) * NHID + col]);
        *(bf16x8*)&W1f[(size_t)idx * 8] = frag;
    } else if (idx < 2048 + 384) {           // 3 ct * 2 ks * 64 lanes
        int i2 = idx - 2048;
        int lane = i2 & 63, ctks = i2 >> 6;
        int ks = ctks & 1, ct = ctks >> 1;
        int col = ct * 16 + (lane & 15);
        int r0 = ks * 32 + (lane >> 4) * 8;
        bf16x8 frag;
        #pragma unroll
        for (int j = 0; j < 8; ++j)
            frag[j] = (short)((col < NCLASS) ? f2bf(W2[(r0 + j) * NCLASS + col]) : 0);
        *(bf16x8*)&W2f[(size_t)i2 * 8] = frag;
    }
}

// ---------------- GEMM1: xW1b = bf16( x @ W1 ) via MFMA ----------------

__global__ __launch_bounds__(256) void k_gemm1(const float* __restrict__ x,
                                               const ushort* __restrict__ W1f,
                                               ushort* __restrict__ xW1b) {
    __shared__ ushort sX[16 * 256];          // 8 KB
    int tid = threadIdx.x;
    int w = tid >> 6, lane = tid & 63;
    int row0 = blockIdx.x * 16;

    bf16x8 Bf[8];
    #pragma unroll
    for (int ks = 0; ks < 8; ++ks)
        Bf[ks] = *(const bf16x8*)&W1f[(size_t)((w * 8 + ks) * 64 + lane) * 8];

    {
        int row = tid & 15;
        int colbase = (tid >> 4) * 16;
        const float* xp = x + (size_t)(row0 + row) * NFEAT + colbase;
        #pragma unroll
        for (int c2 = 0; c2 < 2; ++c2) {
            float4 v0 = *(const float4*)(xp + c2 * 8);
            float4 v1 = *(const float4*)(xp + c2 * 8 + 4);
            bf16x8 fr;
            fr[0] = (short)f2bf(v0.x); fr[1] = (short)f2bf(v0.y);
            fr[2] = (short)f2bf(v0.z); fr[3] = (short)f2bf(v0.w);
            fr[4] = (short)f2bf(v1.x); fr[5] = (short)f2bf(v1.y);
            fr[6] = (short)f2bf(v1.z); fr[7] = (short)f2bf(v1.w);
            int chunk = colbase / 8 + c2;                 // 0..31
            *(bf16x8*)&sX[row * 256 + ((chunk ^ (row & 7)) * 8)] = fr;
        }
    }
    __syncthreads();

    f32x4 acc = {0.f, 0.f, 0.f, 0.f};
    int arow = lane & 15;
    #pragma unroll
    for (int ks = 0; ks < 8; ++ks) {
        int chunk = ks * 4 + (lane >> 4);
        bf16x8 Af = *(const bf16x8*)&sX[arow * 256 + ((chunk ^ (arow & 7)) * 8)];
        acc = __builtin_amdgcn_mfma_f32_16x16x32_bf16(Af, Bf[ks], acc, 0, 0, 0);
    }
    int col = w * 16 + (lane & 15);
    int rbase = row0 + (lane >> 4) * 4;
    #pragma unroll
    for (int r = 0; r < 4; ++r)
        xW1b[(size_t)(rbase + r) * NHID + col] = f2bf(acc[r]);
}

// ---------------- SPMM1 (bucketed) + bias + ReLU -> h (bf16) ----------------
// 4 waves/block, one bucket per wave, wave-private LDS slab -> no barriers.
__global__ __launch_bounds__(256) void k_spmm1b(const ushort* __restrict__ xW1b,
                                                const int* __restrict__ bstart,
                                                const int* __restrict__ bcur,
                                                const int2* __restrict__ binned,
                                                const float* __restrict__ b1,
                                                ushort* __restrict__ h_b) {
    __shared__ float accs[4][NPB * NHID];    // 16 KB
    int wv = threadIdx.x >> 6, lane = threadIdx.x & 63;
    int b = blockIdx.x * 4 + wv;
    float* acc = accs[wv];
    #pragma unroll
    for (int n = 0; n < NPB; ++n) acc[n * NHID + lane] = 0.f;
    if (b < NB) {
        for (int s = 0; s < NSEG; ++s) {
            int j = bstart[s * NB + b], e = bcur[s * NB + b];
            for (; j + 8 <= e; j += 8) {
                int2 p[8];
                #pragma unroll
                for (int k = 0; k < 8; ++k) p[k] = binned[j + k];
                float g[8];
                #pragma unroll
                for (int k = 0; k < 8; ++k)
                    g[k] = bf2f(xW1b[(p[k].x & 0xFFFF) * NHID + lane]);
                #pragma unroll
                for (int k = 0; k < 8; ++k)
                    acc[(p[k].x >> 16) * NHID + lane] += __int_as_float(p[k].y) * g[k];
            }
            for (; j < e; ++j) {
                int2 p0 = binned[j];
                float g0 = bf2f(xW1b[(p0.x & 0xFFFF) * NHID + lane]);
                acc[(p0.x >> 16) * NHID + lane] += __int_as_float(p0.y) * g0;
            }
        }
        float bias = b1[lane];
        #pragma unroll
        for (int n = 0; n < NPB; ++n) {
            float v = acc[n * NHID + lane] + bias;
            h_b[(size_t)(b * NPB + n) * NHID + lane] = f2bf(v > 0.f ? v : 0.f);
        }
    }
}

// ---------------- GEMM2: hW2b = bf16( h @ W2 ) via MFMA ----------------

__global__ __launch_bounds__(256) void k_gemm2(const ushort* __restrict__ h_b,
                                               const ushort* __restrict__ W2f,
                                               ushort* __restrict__ hW2b) {
    int tid = threadIdx.x;
    int w = tid >> 6, lane = tid & 63;
    int row0 = blockIdx.x * 64 + w * 16;

    f32x4 acc[3] = {{0.f,0.f,0.f,0.f},{0.f,0.f,0.f,0.f},{0.f,0.f,0.f,0.f}};
    #pragma unroll
    for (int ks = 0; ks < 2; ++ks) {
        bf16x8 Af = *(const bf16x8*)&h_b[(size_t)(row0 + (lane & 15)) * NHID
                                         + ks * 32 + (lane >> 4) * 8];
        #pragma unroll
        for (int ct = 0; ct < 3; ++ct) {
            bf16x8 Bf = *(const bf16x8*)&W2f[(size_t)((ct * 2 + ks) * 64 + lane) * 8];
            acc[ct] = __builtin_amdgcn_mfma_f32_16x16x32_bf16(Af, Bf, acc[ct], 0, 0, 0);
        }
    }
    int rbase = row0 + (lane >> 4) * 4;
    #pragma unroll
    for (int ct = 0; ct < 3; ++ct) {
        int col = ct * 16 + (lane & 15);
        if (col < NCLASS) {
            #pragma unroll
            for (int r = 0; r < 4; ++r) {
                int row = rbase + r;
                if (row < N_NODES)
                    hW2b[(size_t)row * NCLASS + col] = f2bf(acc[ct][r]);
            }
        }
    }
}

// ---------------- SPMM2 (bucketed) + bias + log-softmax -> out ----------------
// 4 waves/block, wave-private slab; acc stride 64 so lanes 40..63 are benign.
__global__ __launch_bounds__(256) void k_spmm2b(const ushort* __restrict__ hW2b,
                                                const int* __restrict__ bstart,
                                                const int* __restrict__ bcur,
                                                const int2* __restrict__ binned,
                                                const float* __restrict__ b2,
                                                float* __restrict__ out) {
    __shared__ float accs[4][NPB * 64];      // 16 KB
    int wv = threadIdx.x >> 6, lane = threadIdx.x & 63;
    int b = blockIdx.x * 4 + wv;
    float* acc = accs[wv];
    int lf = lane < NCLASS ? lane : 0;
    #pragma unroll
    for (int n = 0; n < NPB; ++n) acc[n * 64 + lane] = 0.f;
    if (b < NB) {
        for (int s = 0; s < NSEG; ++s) {
            int j = bstart[s * NB + b], e = bcur[s * NB + b];
            for (; j + 8 <= e; j += 8) {
                int2 p[8];
                #pragma unroll
                for (int k = 0; k < 8; ++k) p[k] = binned[j + k];
                float g[8];
                #pragma unroll
                for (int k = 0; k < 8; ++k)
                    g[k] = bf2f(hW2b[(p[k].x & 0xFFFF) * NCLASS + lf]);
                #pragma unroll
                for (int k = 0; k < 8; ++k)
                    acc[(p[k].x >> 16) * 64 + lane] += __int_as_float(p[k].y) * g[k];
            }
            for (; j < e; ++j) {
                int2 p0 = binned[j];
                float g0 = bf2f(hW2b[(p0.x & 0xFFFF) * NCLASS + lf]);
                acc[(p0.x >> 16) * 64 + lane] += __int_as_float(p0.y) * g0;
            }
        }
        float bias = (lane < NCLASS) ? b2[lane] : 0.f;
        for (int n = 0; n < NPB; ++n) {
            float v = (lane < NCLASS) ? (acc[n * 64 + lane] + bias) : -INFINITY;
            float m = v;
            #pragma unroll
            for (int off = 32; off; off >>= 1) m = fmaxf(m, __shfl_xor(m, off));
            float ex = (lane < NCLASS) ? __expf(v - m) : 0.f;
            float ssum = ex;
            #pragma unroll
            for (int off = 32; off; off >>= 1) ssum += __shfl_xor(ssum, off);
            float ls = __logf(ssum);
            if (lane < NCLASS) {
                int node = b * NPB + n;
                out[(size_t)node * NCLASS + lane] = v;
                out[(size_t)N_NODES * NCLASS + (size_t)node * NCLASS + lane] = v - m - ls;
            }
        }
    }
}

// ---------------- launch ----------------

extern "C" void kernel_launch(void* const* d_in, const int* in_sizes, int n_in,
                              void* d_out, int out_size, void* d_ws, size_t ws_size,
                              hipStream_t stream) {
    const float* x    = (const float*)d_in[0];
    const float* W1   = (const float*)d_in[1];
    const float* b1   = (const float*)d_in[2];
    const float* W2   = (const float*)d_in[3];
    const float* b2   = (const float*)d_in[4];
    const float* ewt  = (const float*)d_in[5];
    const int*   esrc = (const int*)d_in[6];
    const int*   edst = (const int*)d_in[7];
    float* out = (float*)d_out;

    // workspace layout (16B-aligned chunks)
    char* p = (char*)d_ws;
    ushort* xW1b = (ushort*)p;   p += (size_t)N_NODES * NHID * 2;      // 6.40 MB
    ushort* h_b  = (ushort*)p;   p += (size_t)NPAD_ROWS * NHID * 2;    // 6.41 MB
    ushort* hW2b = (ushort*)p;   p += (size_t)N_NODES * NCLASS * 2;    // 4.00 MB
    int2*   binned = (int2*)p;   p += (size_t)N_EDGES * 8;             // 6.40 MB
    ushort* W1f  = (ushort*)p;   p += 2048 * 8 * 2;                    // 32 KB
    ushort* W2f  = (ushort*)p;   p += 384 * 8 * 2;                     // 6 KB
    int* bcnt    = (int*)p;      p += NSEG * NB * 4;                   // 87.5 KB
    int* cursor  = (int*)p;      p += 4;
    int* bstart  = (int*)p;      p += NSEG * NB * 4;
    int* bcur    = (int*)p;      p += NSEG * NB * 4;

    hipMemsetAsync(bcnt, 0, (NSEG * NB + 1) * sizeof(int), stream);  // bcnt + cursor

    k_bhist<<<(N_EDGES + 255) / 256, 256, 0, stream>>>(edst, bcnt);
    k_bscan<<<(NSEG * NB + 255) / 256, 256, 0, stream>>>(bcnt, bstart, bcur, cursor);
    k_bin<<<(N_EDGES + 255) / 256, 256, 0, stream>>>(esrc, edst, ewt, bcur, binned);
    k_prep<<<10, 256, 0, stream>>>(W1, W2, W1f, W2f);

    k_gemm1<<<N_NODES / 16, 256, 0, stream>>>(x, W1f, xW1b);
    k_spmm1b<<<(NB + 3) / 4, 256, 0, stream>>>(xW1b, bstart, bcur, binned, b1, h_b);
    k_gemm2<<<NPAD_ROWS / 64, 256, 0, stream>>>(h_b, W2f, hW2b);
    k_spmm2b<<<(NB + 3) / 4, 256, 0, stream>>>(hW2b, bstart, bcur, binned, b2, out);
}

// Round 7
// 269.786 us; speedup vs baseline: 1.1472x; 1.1472x over previous
//
#include <hip/hip_runtime.h>
#include <math.h>

#define N_NODES 50000
#define N_EDGES 800000
#define NFEAT 256
#define NHID 64
#define NCLASS 40
#define NPAD_ROWS 50048   // gemm2 reads h in 64-row blocks: 782*64
#define NPB 4             // nodes per bucket
#define NB  12500         // 50000 / 4

typedef __attribute__((ext_vector_type(8))) short bf16x8;
typedef __attribute__((ext_vector_type(4))) float f32x4;

__device__ __forceinline__ ushort f2bf(float f) {
    unsigned u = __float_as_uint(f);
    u += 0x7FFF + ((u >> 16) & 1);          // round-to-nearest-even
    return (ushort)(u >> 16);
}
__device__ __forceinline__ float bf2f(ushort us) {
    return __uint_as_float(((unsigned)us) << 16);
}

// ---------------- bucket CSR build (flat) ----------------

__global__ void k_bhist(const int* __restrict__ edst, int* __restrict__ bcnt) {
    int e = blockIdx.x * 256 + threadIdx.x;
    if (e < N_EDGES) atomicAdd(&bcnt[edst[e] >> 2], 1);
}

// Wave-aggregated allocation of disjoint bucket ranges; global order irrelevant.
__global__ void k_bscan(const int* __restrict__ bcnt, int* __restrict__ bstart,
                        int* __restrict__ bcur, int* __restrict__ cursor) {
    int i = blockIdx.x * 256 + threadIdx.x;
    int lane = threadIdx.x & 63;
    int c = (i < NB) ? bcnt[i] : 0;
    int incl = c;
    #pragma unroll
    for (int off = 1; off < 64; off <<= 1) {
        int n = __shfl_up(incl, off);
        if (lane >= off) incl += n;
    }
    int total = __shfl(incl, 63);
    int base = 0;
    if (lane == 0) base = atomicAdd(cursor, total);
    base = __shfl(base, 0);
    if (i < NB) {
        int s = base + incl - c;
        bstart[i] = s;
        bcur[i] = s;
    }
}

// Flat scatter: claim slot in bucket range, store packed payload.
__global__ void k_bin(const int* __restrict__ esrc, const int* __restrict__ edst,
                      const float* __restrict__ ewt, int* __restrict__ bcur,
                      int2* __restrict__ binned) {
    int e = blockIdx.x * 256 + threadIdx.x;
    if (e < N_EDGES) {
        int d = edst[e];
        int pos = atomicAdd(&bcur[d >> 2], 1);
        binned[pos] = make_int2(esrc[e] | ((d & 3) << 16), __float_as_int(ewt[e]));
    }
}

// ---------------- prep: W1,W2 -> bf16 fragment-ordered tables ----------------

__global__ void k_prep(const float* __restrict__ W1, const float* __restrict__ W2,
                       ushort* __restrict__ W1f, ushort* __restrict__ W2f) {
    int idx = blockIdx.x * 256 + threadIdx.x;
    if (idx < 2048) {                        // 4 ct * 8 ks * 64 lanes
        int lane = idx & 63, ctks = idx >> 6;
        int ks = ctks & 7, ct = ctks >> 3;
        int col = ct * 16 + (lane & 15);
        int r0 = ks * 32 + (lane >> 4) * 8;
        bf16x8 frag;
        #pragma unroll
        for (int j = 0; j < 8; ++j) frag[j] = (short)f2bf(W1[(r0 + j) * NHID + col]);
        *(bf16x8*)&W1f[(size_t)idx * 8] = frag;
    } else if (idx < 2048 + 384) {           // 3 ct * 2 ks * 64 lanes
        int i2 = idx - 2048;
        int lane = i2 & 63, ctks = i2 >> 6;
        int ks = ctks & 1, ct = ctks >> 1;
        int col = ct * 16 + (lane & 15);
        int r0 = ks * 32 + (lane >> 4) * 8;
        bf16x8 frag;
        #pragma unroll
        for (int j = 0; j < 8; ++j)
            frag[j] = (short)((col < NCLASS) ? f2bf(W2[(r0 + j) * NCLASS + col]) : 0);
        *(bf16x8*)&W2f[(size_t)i2 * 8] = frag;
    }
}

// ---------------- GEMM1: xW1b = bf16( x @ W1 ) via MFMA ----------------

__global__ __launch_bounds__(256) void k_gemm1(const float* __restrict__ x,
                                               const ushort* __restrict__ W1f,
                                               ushort* __restrict__ xW1b) {
    __shared__ ushort sX[16 * 256];          // 8 KB
    int tid = threadIdx.x;
    int w = tid >> 6, lane = tid & 63;
    int row0 = blockIdx.x * 16;

    bf16x8 Bf[8];
    #pragma unroll
    for (int ks = 0; ks < 8; ++ks)
        Bf[ks] = *(const bf16x8*)&W1f[(size_t)((w * 8 + ks) * 64 + lane) * 8];

    {
        int row = tid & 15;
        int colbase = (tid >> 4) * 16;
        const float* xp = x + (size_t)(row0 + row) * NFEAT + colbase;
        #pragma unroll
        for (int c2 = 0; c2 < 2; ++c2) {
            float4 v0 = *(const float4*)(xp + c2 * 8);
            float4 v1 = *(const float4*)(xp + c2 * 8 + 4);
            bf16x8 fr;
            fr[0] = (short)f2bf(v0.x); fr[1] = (short)f2bf(v0.y);
            fr[2] = (short)f2bf(v0.z); fr[3] = (short)f2bf(v0.w);
            fr[4] = (short)f2bf(v1.x); fr[5] = (short)f2bf(v1.y);
            fr[6] = (short)f2bf(v1.z); fr[7] = (short)f2bf(v1.w);
            int chunk = colbase / 8 + c2;                 // 0..31
            *(bf16x8*)&sX[row * 256 + ((chunk ^ (row & 7)) * 8)] = fr;
        }
    }
    __syncthreads();

    f32x4 acc = {0.f, 0.f, 0.f, 0.f};
    int arow = lane & 15;
    #pragma unroll
    for (int ks = 0; ks < 8; ++ks) {
        int chunk = ks * 4 + (lane >> 4);
        bf16x8 Af = *(const bf16x8*)&sX[arow * 256 + ((chunk ^ (arow & 7)) * 8)];
        acc = __builtin_amdgcn_mfma_f32_16x16x32_bf16(Af, Bf[ks], acc, 0, 0, 0);
    }
    int col = w * 16 + (lane & 15);
    int rbase = row0 + (lane >> 4) * 4;
    #pragma unroll
    for (int r = 0; r < 4; ++r)
        xW1b[(size_t)(rbase + r) * NHID + col] = f2bf(acc[r]);
}

// ---------------- SPMM1 (bucketed) + bias + ReLU -> h (bf16) ----------------
// 4 waves/block, one 4-node bucket per wave, wave-private 1KB slab, no barriers.
__global__ __launch_bounds__(256) void k_spmm1b(const ushort* __restrict__ xW1b,
                                                const int* __restrict__ bstart,
                                                const int* __restrict__ bcur,
                                                const int2* __restrict__ binned,
                                                const float* __restrict__ b1,
                                                ushort* __restrict__ h_b) {
    __shared__ float accs[4][NPB * NHID];    // 4 KB
    int wv = threadIdx.x >> 6, lane = threadIdx.x & 63;
    int b = blockIdx.x * 4 + wv;
    float* acc = accs[wv];
    #pragma unroll
    for (int n = 0; n < NPB; ++n) acc[n * NHID + lane] = 0.f;

    int j = bstart[b], e = bcur[b];
    for (; j + 8 <= e; j += 8) {
        int2 p[8];
        #pragma unroll
        for (int k = 0; k < 8; ++k) p[k] = binned[j + k];
        float g[8];
        #pragma unroll
        for (int k = 0; k < 8; ++k)
            g[k] = bf2f(xW1b[(p[k].x & 0xFFFF) * NHID + lane]);
        #pragma unroll
        for (int k = 0; k < 8; ++k)
            acc[(p[k].x >> 16) * NHID + lane] += __int_as_float(p[k].y) * g[k];
    }
    for (; j < e; ++j) {
        int2 p0 = binned[j];
        float g0 = bf2f(xW1b[(p0.x & 0xFFFF) * NHID + lane]);
        acc[(p0.x >> 16) * NHID + lane] += __int_as_float(p0.y) * g0;
    }

    float bias = b1[lane];
    #pragma unroll
    for (int n = 0; n < NPB; ++n) {
        float v = acc[n * NHID + lane] + bias;
        h_b[(size_t)(b * NPB + n) * NHID + lane] = f2bf(v > 0.f ? v : 0.f);
    }
}

// ---------------- GEMM2: hW2b = bf16( h @ W2 ) via MFMA ----------------

__global__ __launch_bounds__(256) void k_gemm2(const ushort* __restrict__ h_b,
                                               const ushort* __restrict__ W2f,
                                               ushort* __restrict__ hW2b) {
    int tid = threadIdx.x;
    int w = tid >> 6, lane = tid & 63;
    int row0 = blockIdx.x * 64 + w * 16;

    f32x4 acc[3] = {{0.f,0.f,0.f,0.f},{0.f,0.f,0.f,0.f},{0.f,0.f,0.f,0.f}};
    #pragma unroll
    for (int ks = 0; ks < 2; ++ks) {
        bf16x8 Af = *(const bf16x8*)&h_b[(size_t)(row0 + (lane & 15)) * NHID
                                         + ks * 32 + (lane >> 4) * 8];
        #pragma unroll
        for (int ct = 0; ct < 3; ++ct) {
            bf16x8 Bf = *(const bf16x8*)&W2f[(size_t)((ct * 2 + ks) * 64 + lane) * 8];
            acc[ct] = __builtin_amdgcn_mfma_f32_16x16x32_bf16(Af, Bf, acc[ct], 0, 0, 0);
        }
    }
    int rbase = row0 + (lane >> 4) * 4;
    #pragma unroll
    for (int ct = 0; ct < 3; ++ct) {
        int col = ct * 16 + (lane & 15);
        if (col < NCLASS) {
            #pragma unroll
            for (int r = 0; r < 4; ++r) {
                int row = rbase + r;
                if (row < N_NODES)
                    hW2b[(size_t)row * NCLASS + col] = f2bf(acc[ct][r]);
            }
        }
    }
}

// ---------------- SPMM2 (bucketed) + bias + log-softmax -> out ----------------
// 4 waves/block, wave-private slab; acc stride 64 so lanes 40..63 are benign.
__global__ __launch_bounds__(256) void k_spmm2b(const ushort* __restrict__ hW2b,
                                                const int* __restrict__ bstart,
                                                const int* __restrict__ bcur,
                                                const int2* __restrict__ binned,
                                                const float* __restrict__ b2,
                                                float* __restrict__ out) {
    __shared__ float accs[4][NPB * 64];      // 4 KB
    int wv = threadIdx.x >> 6, lane = threadIdx.x & 63;
    int b = blockIdx.x * 4 + wv;
    float* acc = accs[wv];
    int lf = lane < NCLASS ? lane : 0;
    #pragma unroll
    for (int n = 0; n < NPB; ++n) acc[n * 64 + lane] = 0.f;

    int j = bstart[b], e = bcur[b];
    for (; j + 8 <= e; j += 8) {
        int2 p[8];
        #pragma unroll
        for (int k = 0; k < 8; ++k) p[k] = binned[j + k];
        float g[8];
        #pragma unroll
        for (int k = 0; k < 8; ++k)
            g[k] = bf2f(hW2b[(p[k].x & 0xFFFF) * NCLASS + lf]);
        #pragma unroll
        for (int k = 0; k < 8; ++k)
            acc[(p[k].x >> 16) * 64 + lane] += __int_as_float(p[k].y) * g[k];
    }
    for (; j < e; ++j) {
        int2 p0 = binned[j];
        float g0 = bf2f(hW2b[(p0.x & 0xFFFF) * NCLASS + lf]);
        acc[(p0.x >> 16) * 64 + lane] += __int_as_float(p0.y) * g0;
    }

    float bias = (lane < NCLASS) ? b2[lane] : 0.f;
    #pragma unroll
    for (int n = 0; n < NPB; ++n) {
        float v = (lane < NCLASS) ? (acc[n * 64 + lane] + bias) : -INFINITY;
        float m = v;
        #pragma unroll
        for (int off = 32; off; off >>= 1) m = fmaxf(m, __shfl_xor(m, off));
        float ex = (lane < NCLASS) ? __expf(v - m) : 0.f;
        float ssum = ex;
        #pragma unroll
        for (int off = 32; off; off >>= 1) ssum += __shfl_xor(ssum, off);
        float ls = __logf(ssum);
        if (lane < NCLASS) {
            int node = b * NPB + n;
            out[(size_t)node * NCLASS + lane] = v;
            out[(size_t)N_NODES * NCLASS + (size_t)node * NCLASS + lane] = v - m - ls;
        }
    }
}

// ---------------- launch ----------------

extern "C" void kernel_launch(void* const* d_in, const int* in_sizes, int n_in,
                              void* d_out, int out_size, void* d_ws, size_t ws_size,
                              hipStream_t stream) {
    const float* x    = (const float*)d_in[0];
    const float* W1   = (const float*)d_in[1];
    const float* b1   = (const float*)d_in[2];
    const float* W2   = (const float*)d_in[3];
    const float* b2   = (const float*)d_in[4];
    const float* ewt  = (const float*)d_in[5];
    const int*   esrc = (const int*)d_in[6];
    const int*   edst = (const int*)d_in[7];
    float* out = (float*)d_out;

    // workspace layout (16B-aligned chunks)
    char* p = (char*)d_ws;
    ushort* xW1b = (ushort*)p;   p += (size_t)N_NODES * NHID * 2;      // 6.40 MB
    ushort* h_b  = (ushort*)p;   p += (size_t)NPAD_ROWS * NHID * 2;    // 6.41 MB
    ushort* hW2b = (ushort*)p;   p += (size_t)N_NODES * NCLASS * 2;    // 4.00 MB
    int2*   binned = (int2*)p;   p += (size_t)N_EDGES * 8;             // 6.40 MB
    ushort* W1f  = (ushort*)p;   p += 2048 * 8 * 2;                    // 32 KB
    ushort* W2f  = (ushort*)p;   p += 384 * 8 * 2;                     // 6 KB
    int* bcnt    = (int*)p;      p += NB * 4;                          // 50 KB
    int* cursor  = (int*)p;      p += 4;
    int* bstart  = (int*)p;      p += NB * 4;
    int* bcur    = (int*)p;      p += NB * 4;

    hipMemsetAsync(bcnt, 0, (NB + 1) * sizeof(int), stream);  // bcnt + cursor

    k_bhist<<<(N_EDGES + 255) / 256, 256, 0, stream>>>(edst, bcnt);
    k_bscan<<<(NB + 255) / 256, 256, 0, stream>>>(bcnt, bstart, bcur, cursor);
    k_bin<<<(N_EDGES + 255) / 256, 256, 0, stream>>>(esrc, edst, ewt, bcur, binned);
    k_prep<<<10, 256, 0, stream>>>(W1, W2, W1f, W2f);

    k_gemm1<<<N_NODES / 16, 256, 0, stream>>>(x, W1f, xW1b);
    k_spmm1b<<<NB / 4, 256, 0, stream>>>(xW1b, bstart, bcur, binned, b1, h_b);
    k_gemm2<<<NPAD_ROWS / 64, 256, 0, stream>>>(h_b, W2f, hW2b);
    k_spmm2b<<<NB / 4, 256, 0, stream>>>(hW2b, bstart, bcur, binned, b2, out);
}

// Round 9
// 211.995 us; speedup vs baseline: 1.4599x; 1.2726x over previous
//
#include <hip/hip_runtime.h>
#include <math.h>

#define N_NODES 50000
#define N_EDGES 800000
#define NFEAT 256
#define NHID 64
#define NCLASS 40
#define NPAD_ROWS 50048   // gemm2 reads h in 64-row blocks: 782*64
#define NPB 16            // nodes per bucket
#define NB  3125          // 50000 / 16
#define BIN_EPB 8192      // edges per binning block (1024 threads, 8 rounds)

typedef __attribute__((ext_vector_type(8))) short bf16x8;
typedef __attribute__((ext_vector_type(4))) float f32x4;

__device__ __forceinline__ ushort f2bf(float f) {
    unsigned u = __float_as_uint(f);
    u += 0x7FFF + ((u >> 16) & 1);          // round-to-nearest-even
    return (ushort)(u >> 16);
}
__device__ __forceinline__ float bf2f(ushort us) {
    return __uint_as_float(((unsigned)us) << 16);
}

// ---------------- bucket CSR build ----------------

// LDS-aggregated histogram: 3125 counters, one flush per block.
__global__ __launch_bounds__(256) void k_bhist(const int* __restrict__ edst,
                                               int* __restrict__ bcnt) {
    __shared__ int lh[NB];
    int tid = threadIdx.x;
    for (int i = tid; i < NB; i += 256) lh[i] = 0;
    __syncthreads();
    int base = blockIdx.x * 4096;
    #pragma unroll
    for (int k = 0; k < 4096; k += 256) {
        int e = base + k + tid;
        if (e < N_EDGES) atomicAdd(&lh[edst[e] >> 4], 1);
    }
    __syncthreads();
    for (int i = tid; i < NB; i += 256) {
        int c = lh[i];
        if (c) atomicAdd(&bcnt[i], c);
    }
}

// Wave-aggregated allocation of disjoint bucket ranges; global order irrelevant.
__global__ void k_bscan(const int* __restrict__ bcnt, int* __restrict__ bstart,
                        int* __restrict__ bcur, int* __restrict__ cursor) {
    int i = blockIdx.x * 256 + threadIdx.x;
    int lane = threadIdx.x & 63;
    int c = (i < NB) ? bcnt[i] : 0;
    int incl = c;
    #pragma unroll
    for (int off = 1; off < 64; off <<= 1) {
        int n = __shfl_up(incl, off);
        if (lane >= off) incl += n;
    }
    int total = __shfl(incl, 63);
    int base = 0;
    if (lane == 0) base = atomicAdd(cursor, total);
    base = __shfl(base, 0);
    if (i < NB) {
        int s = base + incl - c;
        bstart[i] = s;
        bcur[i] = s;
    }
}

// Two-phase block-local binning at 1024 threads (16 waves of latency hiding):
// LDS count -> claim contiguous per-bucket ranges -> clustered scatter.
__global__ __launch_bounds__(1024) void k_bin(const int* __restrict__ esrc,
                                              const int* __restrict__ edst,
                                              const float* __restrict__ ewt,
                                              int* __restrict__ bcur,
                                              int2* __restrict__ binned) {
    __shared__ int lcnt[NB];
    __shared__ int lbase[NB];
    int tid = threadIdx.x;
    for (int i = tid; i < NB; i += 1024) lcnt[i] = 0;
    __syncthreads();
    int base = blockIdx.x * BIN_EPB;
    #pragma unroll
    for (int k = 0; k < BIN_EPB; k += 1024) {
        int e = base + k + tid;
        if (e < N_EDGES) atomicAdd(&lcnt[edst[e] >> 4], 1);
    }
    __syncthreads();
    for (int i = tid; i < NB; i += 1024) {
        int c = lcnt[i];
        lbase[i] = c ? atomicAdd(&bcur[i], c) : 0;
        lcnt[i] = 0;
    }
    __syncthreads();
    #pragma unroll
    for (int k = 0; k < BIN_EPB; k += 1024) {
        int e = base + k + tid;
        if (e < N_EDGES) {
            int d = edst[e];
            int b = d >> 4;
            int pos = lbase[b] + atomicAdd(&lcnt[b], 1);
            binned[pos] = make_int2(esrc[e] | ((d & 15) << 16), __float_as_int(ewt[e]));
        }
    }
}

// ---------------- prep: W1,W2 -> bf16 fragment-ordered tables ----------------

__global__ void k_prep(const float* __restrict__ W1, const float* __restrict__ W2,
                       ushort* __restrict__ W1f, ushort* __restrict__ W2f) {
    int idx = blockIdx.x * 256 + threadIdx.x;
    if (idx < 2048) {                        // 4 ct * 8 ks * 64 lanes
        int lane = idx & 63, ctks = idx >> 6;
        int ks = ctks & 7, ct = ctks >> 3;
        int col = ct * 16 + (lane & 15);
        int r0 = ks * 32 + (lane >> 4) * 8;
        bf16x8 frag;
        #pragma unroll
        for (int j = 0; j < 8; ++j) frag[j] = (short)f2bf(W1[(r0 + j) * NHID + col]);
        *(bf16x8*)&W1f[(size_t)idx * 8] = frag;
    } else if (idx < 2048 + 384) {           // 3 ct * 2 ks * 64 lanes
        int i2 = idx - 2048;
        int lane = i2 & 63, ctks = i2 >> 6;
        int ks = ctks & 1, ct = ctks >> 1;
        int col = ct * 16 + (lane & 15);
        int r0 = ks * 32 + (lane >> 4) * 8;
        bf16x8 frag;
        #pragma unroll
        for (int j = 0; j < 8; ++j)
            frag[j] = (short)((col < NCLASS) ? f2bf(W2[(r0 + j) * NCLASS + col]) : 0);
        *(bf16x8*)&W2f[(size_t)i2 * 8] = frag;
    }
}

// ---------------- GEMM1: xW1b = bf16( x @ W1 ) via MFMA ----------------

__global__ __launch_bounds__(256) void k_gemm1(const float* __restrict__ x,
                                               const ushort* __restrict__ W1f,
                                               ushort* __restrict__ xW1b) {
    __shared__ ushort sX[16 * 256];          // 8 KB
    int tid = threadIdx.x;
    int w = tid >> 6, lane = tid & 63;
    int row0 = blockIdx.x * 16;

    bf16x8 Bf[8];
    #pragma unroll
    for (int ks = 0; ks < 8; ++ks)
        Bf[ks] = *(const bf16x8*)&W1f[(size_t)((w * 8 + ks) * 64 + lane) * 8];

    {
        int row = tid & 15;
        int colbase = (tid >> 4) * 16;
        const float* xp = x + (size_t)(row0 + row) * NFEAT + colbase;
        #pragma unroll
        for (int c2 = 0; c2 < 2; ++c2) {
            float4 v0 = *(const float4*)(xp + c2 * 8);
            float4 v1 = *(const float4*)(xp + c2 * 8 + 4);
            bf16x8 fr;
            fr[0] = (short)f2bf(v0.x); fr[1] = (short)f2bf(v0.y);
            fr[2] = (short)f2bf(v0.z); fr[3] = (short)f2bf(v0.w);
            fr[4] = (short)f2bf(v1.x); fr[5] = (short)f2bf(v1.y);
            fr[6] = (short)f2bf(v1.z); fr[7] = (short)f2bf(v1.w);
            int chunk = colbase / 8 + c2;                 // 0..31
            *(bf16x8*)&sX[row * 256 + ((chunk ^ (row & 7)) * 8)] = fr;
        }
    }
    __syncthreads();

    f32x4 acc = {0.f, 0.f, 0.f, 0.f};
    int arow = lane & 15;
    #pragma unroll
    for (int ks = 0; ks < 8; ++ks) {
        int chunk = ks * 4 + (lane >> 4);
        bf16x8 Af = *(const bf16x8*)&sX[arow * 256 + ((chunk ^ (arow & 7)) * 8)];
        acc = __builtin_amdgcn_mfma_f32_16x16x32_bf16(Af, Bf[ks], acc, 0, 0, 0);
    }
    int col = w * 16 + (lane & 15);
    int rbase = row0 + (lane >> 4) * 4;
    #pragma unroll
    for (int r = 0; r < 4; ++r)
        xW1b[(size_t)(rbase + r) * NHID + col] = f2bf(acc[r]);
}

// ---------------- SPMM1: 4 waves co-process ONE 16-node bucket ----------------
// Wave wv takes quarter of the edge range into a private slab; barrier; 4-way
// cross-slab reduce + bias + ReLU (wave wv finalizes nodes wv*4..wv*4+3).
__global__ __launch_bounds__(256) void k_spmm1b(const ushort* __restrict__ xW1b,
                                                const int* __restrict__ bstart,
                                                const int* __restrict__ bcur,
                                                const int2* __restrict__ binned,
                                                const float* __restrict__ b1,
                                                ushort* __restrict__ h_b) {
    __shared__ float accs[4][NPB * NHID];    // 16 KB
    int wv = threadIdx.x >> 6, lane = threadIdx.x & 63;
    int b = blockIdx.x;
    float* acc = accs[wv];
    #pragma unroll
    for (int n = 0; n < NPB; ++n) acc[n * NHID + lane] = 0.f;

    int s = bstart[b], e = bcur[b];
    int len = e - s;
    int q = (len + 3) >> 2;
    int j = s + wv * q;
    int je = min(j + q, e);
    for (; j + 8 <= je; j += 8) {
        int2 p[8];
        #pragma unroll
        for (int k = 0; k < 8; ++k) p[k] = binned[j + k];
        float g[8];
        #pragma unroll
        for (int k = 0; k < 8; ++k)
            g[k] = bf2f(xW1b[(p[k].x & 0xFFFF) * NHID + lane]);
        #pragma unroll
        for (int k = 0; k < 8; ++k)
            acc[(p[k].x >> 16) * NHID + lane] += __int_as_float(p[k].y) * g[k];
    }
    for (; j < je; ++j) {
        int2 p0 = binned[j];
        float g0 = bf2f(xW1b[(p0.x & 0xFFFF) * NHID + lane]);
        acc[(p0.x >> 16) * NHID + lane] += __int_as_float(p0.y) * g0;
    }
    __syncthreads();

    float bias = b1[lane];
    #pragma unroll
    for (int i = 0; i < 4; ++i) {
        int n = wv * 4 + i;
        float v = accs[0][n * NHID + lane] + accs[1][n * NHID + lane]
                + accs[2][n * NHID + lane] + accs[3][n * NHID + lane] + bias;
        h_b[(size_t)(b * NPB + n) * NHID + lane] = f2bf(v > 0.f ? v : 0.f);
    }
}

// ---------------- GEMM2: hW2b = bf16( h @ W2 ) via MFMA ----------------

__global__ __launch_bounds__(256) void k_gemm2(const ushort* __restrict__ h_b,
                                               const ushort* __restrict__ W2f,
                                               ushort* __restrict__ hW2b) {
    int tid = threadIdx.x;
    int w = tid >> 6, lane = tid & 63;
    int row0 = blockIdx.x * 64 + w * 16;

    f32x4 acc[3] = {{0.f,0.f,0.f,0.f},{0.f,0.f,0.f,0.f},{0.f,0.f,0.f,0.f}};
    #pragma unroll
    for (int ks = 0; ks < 2; ++ks) {
        bf16x8 Af = *(const bf16x8*)&h_b[(size_t)(row0 + (lane & 15)) * NHID
                                         + ks * 32 + (lane >> 4) * 8];
        #pragma unroll
        for (int ct = 0; ct < 3; ++ct) {
            bf16x8 Bf = *(const bf16x8*)&W2f[(size_t)((ct * 2 + ks) * 64 + lane) * 8];
            acc[ct] = __builtin_amdgcn_mfma_f32_16x16x32_bf16(Af, Bf, acc[ct], 0, 0, 0);
        }
    }
    int rbase = row0 + (lane >> 4) * 4;
    #pragma unroll
    for (int ct = 0; ct < 3; ++ct) {
        int col = ct * 16 + (lane & 15);
        if (col < NCLASS) {
            #pragma unroll
            for (int r = 0; r < 4; ++r) {
                int row = rbase + r;
                if (row < N_NODES)
                    hW2b[(size_t)row * NCLASS + col] = f2bf(acc[ct][r]);
            }
        }
    }
}

// ---------------- SPMM2: 4 waves per bucket + bias + log-softmax ----------------
// Slab stride 64 so lanes 40..63 accumulate harmlessly into unused columns.
__global__ __launch_bounds__(256) void k_spmm2b(const ushort* __restrict__ hW2b,
                                                const int* __restrict__ bstart,
                                                const int* __restrict__ bcur,
                                                const int2* __restrict__ binned,
                                                const float* __restrict__ b2,
                                                float* __restrict__ out) {
    __shared__ float accs[4][NPB * 64];      // 16 KB
    int wv = threadIdx.x >> 6, lane = threadIdx.x & 63;
    int b = blockIdx.x;
    float* acc = accs[wv];
    int lf = lane < NCLASS ? lane : 0;
    #pragma unroll
    for (int n = 0; n < NPB; ++n) acc[n * 64 + lane] = 0.f;

    int s = bstart[b], e = bcur[b];
    int len = e - s;
    int q = (len + 3) >> 2;
    int j = s + wv * q;
    int je = min(j + q, e);
    for (; j + 8 <= je; j += 8) {
        int2 p[8];
        #pragma unroll
        for (int k = 0; k < 8; ++k) p[k] = binned[j + k];
        float g[8];
        #pragma unroll
        for (int k = 0; k < 8; ++k)
            g[k] = bf2f(hW2b[(p[k].x & 0xFFFF) * NCLASS + lf]);
        #pragma unroll
        for (int k = 0; k < 8; ++k)
            acc[(p[k].x >> 16) * 64 + lane] += __int_as_float(p[k].y) * g[k];
    }
    for (; j < je; ++j) {
        int2 p0 = binned[j];
        float g0 = bf2f(hW2b[(p0.x & 0xFFFF) * NCLASS + lf]);
        acc[(p0.x >> 16) * 64 + lane] += __int_as_float(p0.y) * g0;
    }
    __syncthreads();

    float bias = (lane < NCLASS) ? b2[lane] : 0.f;
    #pragma unroll
    for (int i = 0; i < 4; ++i) {
        int n = wv * 4 + i;
        float vs = accs[0][n * 64 + lane] + accs[1][n * 64 + lane]
                 + accs[2][n * 64 + lane] + accs[3][n * 64 + lane];
        float v = (lane < NCLASS) ? (vs + bias) : -INFINITY;
        float m = v;
        #pragma unroll
        for (int off = 32; off; off >>= 1) m = fmaxf(m, __shfl_xor(m, off));
        float ex = (lane < NCLASS) ? __expf(v - m) : 0.f;
        float ssum = ex;
        #pragma unroll
        for (int off = 32; off; off >>= 1) ssum += __shfl_xor(ssum, off);
        float ls = __logf(ssum);
        if (lane < NCLASS) {
            int node = b * NPB + n;
            out[(size_t)node * NCLASS + lane] = v;
            out[(size_t)N_NODES * NCLASS + (size_t)node * NCLASS + lane] = v - m - ls;
        }
    }
}

// ---------------- launch ----------------

extern "C" void kernel_launch(void* const* d_in, const int* in_sizes, int n_in,
                              void* d_out, int out_size, void* d_ws, size_t ws_size,
                              hipStream_t stream) {
    const float* x    = (const float*)d_in[0];
    const float* W1   = (const float*)d_in[1];
    const float* b1   = (const float*)d_in[2];
    const float* W2   = (const float*)d_in[3];
    const float* b2   = (const float*)d_in[4];
    const float* ewt  = (const float*)d_in[5];
    const int*   esrc = (const int*)d_in[6];
    const int*   edst = (const int*)d_in[7];
    float* out = (float*)d_out;

    // workspace layout (16B-aligned chunks)
    char* p = (char*)d_ws;
    ushort* xW1b = (ushort*)p;   p += (size_t)N_NODES * NHID * 2;      // 6.40 MB
    ushort* h_b  = (ushort*)p;   p += (size_t)NPAD_ROWS * NHID * 2;    // 6.41 MB
    ushort* hW2b = (ushort*)p;   p += (size_t)N_NODES * NCLASS * 2;    // 4.00 MB
    int2*   binned = (int2*)p;   p += (size_t)N_EDGES * 8;             // 6.40 MB
    ushort* W1f  = (ushort*)p;   p += 2048 * 8 * 2;                    // 32 KB
    ushort* W2f  = (ushort*)p;   p += 384 * 8 * 2;                     // 6 KB
    int* bcnt    = (int*)p;      p += NB * 4;                          // 12.5 KB
    int* cursor  = (int*)p;      p += 4;
    int* bstart  = (int*)p;      p += NB * 4;
    int* bcur    = (int*)p;      p += NB * 4;

    hipMemsetAsync(bcnt, 0, (NB + 1) * sizeof(int), stream);  // bcnt + cursor

    k_bhist<<<(N_EDGES + 4095) / 4096, 256, 0, stream>>>(edst, bcnt);
    k_bscan<<<(NB + 255) / 256, 256, 0, stream>>>(bcnt, bstart, bcur, cursor);
    k_bin<<<(N_EDGES + BIN_EPB - 1) / BIN_EPB, 1024, 0, stream>>>(esrc, edst, ewt, bcur, binned);
    k_prep<<<10, 256, 0, stream>>>(W1, W2, W1f, W2f);

    k_gemm1<<<N_NODES / 16, 256, 0, stream>>>(x, W1f, xW1b);
    k_spmm1b<<<NB, 256, 0, stream>>>(xW1b, bstart, bcur, binned, b1, h_b);
    k_gemm2<<<NPAD_ROWS / 64, 256, 0, stream>>>(h_b, W2f, hW2b);
    k_spmm2b<<<NB, 256, 0, stream>>>(hW2b, bstart, bcur, binned, b2, out);
}

// Round 10
// 200.494 us; speedup vs baseline: 1.5436x; 1.0574x over previous
//
#include <hip/hip_runtime.h>
#include <math.h>

#define N_NODES 50000
#define N_EDGES 800000
#define NFEAT 256
#define NHID 64
#define NCLASS 40
#define NPB 16            // nodes per bucket
#define NB  3125          // 50000 / 16
#define BIN_EPB 8192      // edges per binning block (1024 threads, 8 rounds)
#define NHB 196           // hist blocks: ceil(800000/4096)
#define ACC2S 68          // spmm2f acc row stride (pad vs 16-way xpose conflict)

typedef __attribute__((ext_vector_type(8))) short bf16x8;
typedef __attribute__((ext_vector_type(4))) float f32x4;

__device__ __forceinline__ ushort f2bf(float f) {
    unsigned u = __float_as_uint(f);
    u += 0x7FFF + ((u >> 16) & 1);          // round-to-nearest-even
    return (ushort)(u >> 16);
}
__device__ __forceinline__ float bf2f(ushort us) {
    return __uint_as_float(((unsigned)us) << 16);
}

// -------- fused: LDS-aggregated bucket histogram + weight-fragment prep --------
__global__ __launch_bounds__(256) void k_histprep(const int* __restrict__ edst,
                                                  int* __restrict__ bcnt,
                                                  const float* __restrict__ W1,
                                                  const float* __restrict__ W2,
                                                  ushort* __restrict__ W1f,
                                                  ushort* __restrict__ W2f) {
    __shared__ int lh[NB];
    int tid = threadIdx.x;
    if (blockIdx.x >= NHB) {                 // ---- prep path ----
        int idx = (blockIdx.x - NHB) * 256 + tid;
        if (idx < 2048) {                    // W1f: 4 ct * 8 ks * 64 lanes
            int lane = idx & 63, ctks = idx >> 6;
            int ks = ctks & 7, ct = ctks >> 3;
            int col = ct * 16 + (lane & 15);
            int r0 = ks * 32 + (lane >> 4) * 8;
            bf16x8 frag;
            #pragma unroll
            for (int j = 0; j < 8; ++j) frag[j] = (short)f2bf(W1[(r0 + j) * NHID + col]);
            *(bf16x8*)&W1f[(size_t)idx * 8] = frag;
        } else if (idx < 2048 + 384) {       // W2f: 3 ct * 2 ks * 64 lanes
            int i2 = idx - 2048;
            int lane = i2 & 63, ctks = i2 >> 6;
            int ks = ctks & 1, ct = ctks >> 1;
            int col = ct * 16 + (lane & 15);
            int r0 = ks * 32 + (lane >> 4) * 8;
            bf16x8 frag;
            #pragma unroll
            for (int j = 0; j < 8; ++j)
                frag[j] = (short)((col < NCLASS) ? f2bf(W2[(r0 + j) * NCLASS + col]) : 0);
            *(bf16x8*)&W2f[(size_t)i2 * 8] = frag;
        }
        return;
    }
    // ---- hist path ----
    for (int i = tid; i < NB; i += 256) lh[i] = 0;
    __syncthreads();
    int base = blockIdx.x * 4096;
    #pragma unroll
    for (int k = 0; k < 4096; k += 256) {
        int e = base + k + tid;
        if (e < N_EDGES) atomicAdd(&lh[edst[e] >> 4], 1);
    }
    __syncthreads();
    for (int i = tid; i < NB; i += 256) {
        int c = lh[i];
        if (c) atomicAdd(&bcnt[i], c);
    }
}

// Wave-aggregated allocation of disjoint bucket ranges; global order irrelevant.
__global__ void k_bscan(const int* __restrict__ bcnt, int* __restrict__ bstart,
                        int* __restrict__ bcur, int* __restrict__ cursor) {
    int i = blockIdx.x * 256 + threadIdx.x;
    int lane = threadIdx.x & 63;
    int c = (i < NB) ? bcnt[i] : 0;
    int incl = c;
    #pragma unroll
    for (int off = 1; off < 64; off <<= 1) {
        int n = __shfl_up(incl, off);
        if (lane >= off) incl += n;
    }
    int total = __shfl(incl, 63);
    int base = 0;
    if (lane == 0) base = atomicAdd(cursor, total);
    base = __shfl(base, 0);
    if (i < NB) {
        int s = base + incl - c;
        bstart[i] = s;
        bcur[i] = s;
    }
}

// Two-phase block-local binning at 1024 threads (16 waves of latency hiding):
// LDS count -> claim contiguous per-bucket ranges -> clustered scatter.
__global__ __launch_bounds__(1024) void k_bin(const int* __restrict__ esrc,
                                              const int* __restrict__ edst,
                                              const float* __restrict__ ewt,
                                              int* __restrict__ bcur,
                                              int2* __restrict__ binned) {
    __shared__ int lcnt[NB];
    __shared__ int lbase[NB];
    int tid = threadIdx.x;
    for (int i = tid; i < NB; i += 1024) lcnt[i] = 0;
    __syncthreads();
    int base = blockIdx.x * BIN_EPB;
    #pragma unroll
    for (int k = 0; k < BIN_EPB; k += 1024) {
        int e = base + k + tid;
        if (e < N_EDGES) atomicAdd(&lcnt[edst[e] >> 4], 1);
    }
    __syncthreads();
    for (int i = tid; i < NB; i += 1024) {
        int c = lcnt[i];
        lbase[i] = c ? atomicAdd(&bcur[i], c) : 0;
        lcnt[i] = 0;
    }
    __syncthreads();
    #pragma unroll
    for (int k = 0; k < BIN_EPB; k += 1024) {
        int e = base + k + tid;
        if (e < N_EDGES) {
            int d = edst[e];
            int b = d >> 4;
            int pos = lbase[b] + atomicAdd(&lcnt[b], 1);
            binned[pos] = make_int2(esrc[e] | ((d & 15) << 16), __float_as_int(ewt[e]));
        }
    }
}

// ---------------- GEMM1: xW1b = bf16( x @ W1 ) via MFMA ----------------

__global__ __launch_bounds__(256) void k_gemm1(const float* __restrict__ x,
                                               const ushort* __restrict__ W1f,
                                               ushort* __restrict__ xW1b) {
    __shared__ ushort sX[16 * 256];          // 8 KB
    int tid = threadIdx.x;
    int w = tid >> 6, lane = tid & 63;
    int row0 = blockIdx.x * 16;

    bf16x8 Bf[8];
    #pragma unroll
    for (int ks = 0; ks < 8; ++ks)
        Bf[ks] = *(const bf16x8*)&W1f[(size_t)((w * 8 + ks) * 64 + lane) * 8];

    {
        int row = tid & 15;
        int colbase = (tid >> 4) * 16;
        const float* xp = x + (size_t)(row0 + row) * NFEAT + colbase;
        #pragma unroll
        for (int c2 = 0; c2 < 2; ++c2) {
            float4 v0 = *(const float4*)(xp + c2 * 8);
            float4 v1 = *(const float4*)(xp + c2 * 8 + 4);
            bf16x8 fr;
            fr[0] = (short)f2bf(v0.x); fr[1] = (short)f2bf(v0.y);
            fr[2] = (short)f2bf(v0.z); fr[3] = (short)f2bf(v0.w);
            fr[4] = (short)f2bf(v1.x); fr[5] = (short)f2bf(v1.y);
            fr[6] = (short)f2bf(v1.z); fr[7] = (short)f2bf(v1.w);
            int chunk = colbase / 8 + c2;                 // 0..31
            *(bf16x8*)&sX[row * 256 + ((chunk ^ (row & 7)) * 8)] = fr;
        }
    }
    __syncthreads();

    f32x4 acc = {0.f, 0.f, 0.f, 0.f};
    int arow = lane & 15;
    #pragma unroll
    for (int ks = 0; ks < 8; ++ks) {
        int chunk = ks * 4 + (lane >> 4);
        bf16x8 Af = *(const bf16x8*)&sX[arow * 256 + ((chunk ^ (arow & 7)) * 8)];
        acc = __builtin_amdgcn_mfma_f32_16x16x32_bf16(Af, Bf[ks], acc, 0, 0, 0);
    }
    int col = w * 16 + (lane & 15);
    int rbase = row0 + (lane >> 4) * 4;
    #pragma unroll
    for (int r = 0; r < 4; ++r)
        xW1b[(size_t)(rbase + r) * NHID + col] = f2bf(acc[r]);
}

// ---------------- SPMM1: 4 waves co-process ONE 16-node bucket ----------------
__global__ __launch_bounds__(256) void k_spmm1b(const ushort* __restrict__ xW1b,
                                                const int* __restrict__ bstart,
                                                const int* __restrict__ bcur,
                                                const int2* __restrict__ binned,
                                                const float* __restrict__ b1,
                                                ushort* __restrict__ h_b) {
    __shared__ float accs[4][NPB * NHID];    // 16 KB
    int wv = threadIdx.x >> 6, lane = threadIdx.x & 63;
    int b = blockIdx.x;
    float* acc = accs[wv];
    #pragma unroll
    for (int n = 0; n < NPB; ++n) acc[n * NHID + lane] = 0.f;

    int s = bstart[b], e = bcur[b];
    int len = e - s;
    int q = (len + 3) >> 2;
    int j = s + wv * q;
    int je = min(j + q, e);
    for (; j + 8 <= je; j += 8) {
        int2 p[8];
        #pragma unroll
        for (int k = 0; k < 8; ++k) p[k] = binned[j + k];
        float g[8];
        #pragma unroll
        for (int k = 0; k < 8; ++k)
            g[k] = bf2f(xW1b[(p[k].x & 0xFFFF) * NHID + lane]);
        #pragma unroll
        for (int k = 0; k < 8; ++k)
            acc[(p[k].x >> 16) * NHID + lane] += __int_as_float(p[k].y) * g[k];
    }
    for (; j < je; ++j) {
        int2 p0 = binned[j];
        float g0 = bf2f(xW1b[(p0.x & 0xFFFF) * NHID + lane]);
        acc[(p0.x >> 16) * NHID + lane] += __int_as_float(p0.y) * g0;
    }
    __syncthreads();

    float bias = b1[lane];
    #pragma unroll
    for (int i = 0; i < 4; ++i) {
        int n = wv * 4 + i;
        float v = accs[0][n * NHID + lane] + accs[1][n * NHID + lane]
                + accs[2][n * NHID + lane] + accs[3][n * NHID + lane] + bias;
        h_b[(size_t)(b * NPB + n) * NHID + lane] = f2bf(v > 0.f ? v : 0.f);
    }
}

// ------- SPMM2 fused: (A·h) gathered in f32, then ·W2 via MFMA + softmax -------
// 4 waves gather quarters of the bucket's edges (h rows, 64-wide) into private
// slabs; reduce into slab0; wave 0 projects 16x64 @ 64x48 with 6 MFMAs and does
// per-row (16-lane-group) log-softmax, writing both outputs.
__global__ __launch_bounds__(256) void k_spmm2f(const ushort* __restrict__ h_b,
                                                const int* __restrict__ bstart,
                                                const int* __restrict__ bcur,
                                                const int2* __restrict__ binned,
                                                const ushort* __restrict__ W2f,
                                                const float* __restrict__ b2,
                                                float* __restrict__ out) {
    __shared__ float accs[4][NPB * ACC2S];   // 17 KB
    int wv = threadIdx.x >> 6, lane = threadIdx.x & 63;
    int b = blockIdx.x;
    float* acc = accs[wv];
    #pragma unroll
    for (int n = 0; n < NPB; ++n) acc[n * ACC2S + lane] = 0.f;

    int s = bstart[b], e = bcur[b];
    int len = e - s;
    int q = (len + 3) >> 2;
    int j = s + wv * q;
    int je = min(j + q, e);
    for (; j + 8 <= je; j += 8) {
        int2 p[8];
        #pragma unroll
        for (int k = 0; k < 8; ++k) p[k] = binned[j + k];
        float g[8];
        #pragma unroll
        for (int k = 0; k < 8; ++k)
            g[k] = bf2f(h_b[(p[k].x & 0xFFFF) * NHID + lane]);
        #pragma unroll
        for (int k = 0; k < 8; ++k)
            acc[(p[k].x >> 16) * ACC2S + lane] += __int_as_float(p[k].y) * g[k];
    }
    for (; j < je; ++j) {
        int2 p0 = binned[j];
        float g0 = bf2f(h_b[(p0.x & 0xFFFF) * NHID + lane]);
        acc[(p0.x >> 16) * ACC2S + lane] += __int_as_float(p0.y) * g0;
    }
    __syncthreads();

    // reduce 4 slabs -> slab0 (cols 0..63 only)
    for (int i = threadIdx.x; i < NPB * 64; i += 256) {
        int idx = (i >> 6) * ACC2S + (i & 63);
        accs[0][idx] = accs[0][idx] + accs[1][idx] + accs[2][idx] + accs[3][idx];
    }
    __syncthreads();
    if (wv != 0) return;

    // wave 0: A fragments from slab0 (row = lane&15 = node, col = k)
    bf16x8 Af[2];
    #pragma unroll
    for (int ks = 0; ks < 2; ++ks) {
        const float* ap = &accs[0][(lane & 15) * ACC2S + ks * 32 + (lane >> 4) * 8];
        #pragma unroll
        for (int jj = 0; jj < 8; ++jj) Af[ks][jj] = (short)f2bf(ap[jj]);
    }
    f32x4 cv[3] = {{0.f,0.f,0.f,0.f},{0.f,0.f,0.f,0.f},{0.f,0.f,0.f,0.f}};
    #pragma unroll
    for (int ct = 0; ct < 3; ++ct) {
        #pragma unroll
        for (int ks = 0; ks < 2; ++ks) {
            bf16x8 Bf = *(const bf16x8*)&W2f[(size_t)((ct * 2 + ks) * 64 + lane) * 8];
            cv[ct] = __builtin_amdgcn_mfma_f32_16x16x32_bf16(Af[ks], Bf, cv[ct], 0, 0, 0);
        }
    }
    // softmax: lane-group g = lane>>4 owns rows g*4+i; colg = lane&15.
    int colg = lane & 15;
    int g = lane >> 4;
    float bc0 = b2[colg];
    float bc1 = b2[16 + colg];
    float bc2 = (colg < 8) ? b2[32 + colg] : 0.f;
    #pragma unroll
    for (int i = 0; i < 4; ++i) {
        int node = b * NPB + g * 4 + i;
        float v0 = cv[0][i] + bc0;
        float v1 = cv[1][i] + bc1;
        float v2 = (colg < 8) ? (cv[2][i] + bc2) : -INFINITY;
        float m = fmaxf(fmaxf(v0, v1), v2);
        #pragma unroll
        for (int off = 1; off < 16; off <<= 1) m = fmaxf(m, __shfl_xor(m, off));
        float ex = __expf(v0 - m) + __expf(v1 - m) + ((colg < 8) ? __expf(v2 - m) : 0.f);
        #pragma unroll
        for (int off = 1; off < 16; off <<= 1) ex += __shfl_xor(ex, off);
        float ls = __logf(ex) + m;
        float* o0 = out + (size_t)node * NCLASS;
        float* o1 = o0 + (size_t)N_NODES * NCLASS;
        o0[colg] = v0;            o1[colg] = v0 - ls;
        o0[16 + colg] = v1;       o1[16 + colg] = v1 - ls;
        if (colg < 8) { o0[32 + colg] = v2;  o1[32 + colg] = v2 - ls; }
    }
}

// ---------------- launch ----------------

extern "C" void kernel_launch(void* const* d_in, const int* in_sizes, int n_in,
                              void* d_out, int out_size, void* d_ws, size_t ws_size,
                              hipStream_t stream) {
    const float* x    = (const float*)d_in[0];
    const float* W1   = (const float*)d_in[1];
    const float* b1   = (const float*)d_in[2];
    const float* W2   = (const float*)d_in[3];
    const float* b2   = (const float*)d_in[4];
    const float* ewt  = (const float*)d_in[5];
    const int*   esrc = (const int*)d_in[6];
    const int*   edst = (const int*)d_in[7];
    float* out = (float*)d_out;

    // workspace layout (16B-aligned chunks)
    char* p = (char*)d_ws;
    ushort* xW1b = (ushort*)p;   p += (size_t)N_NODES * NHID * 2;      // 6.40 MB
    ushort* h_b  = (ushort*)p;   p += (size_t)N_NODES * NHID * 2;      // 6.40 MB
    int2*   binned = (int2*)p;   p += (size_t)N_EDGES * 8;             // 6.40 MB
    ushort* W1f  = (ushort*)p;   p += 2048 * 8 * 2;                    // 32 KB
    ushort* W2f  = (ushort*)p;   p += 384 * 8 * 2;                     // 6 KB
    int* bcnt    = (int*)p;      p += NB * 4;                          // 12.5 KB
    int* cursor  = (int*)p;      p += 4;
    int* bstart  = (int*)p;      p += NB * 4;
    int* bcur    = (int*)p;      p += NB * 4;

    hipMemsetAsync(bcnt, 0, (NB + 1) * sizeof(int), stream);  // bcnt + cursor

    k_histprep<<<NHB + 10, 256, 0, stream>>>(edst, bcnt, W1, W2, W1f, W2f);
    k_bscan<<<(NB + 255) / 256, 256, 0, stream>>>(bcnt, bstart, bcur, cursor);
    k_bin<<<(N_EDGES + BIN_EPB - 1) / BIN_EPB, 1024, 0, stream>>>(esrc, edst, ewt, bcur, binned);

    k_gemm1<<<N_NODES / 16, 256, 0, stream>>>(x, W1f, xW1b);
    k_spmm1b<<<NB, 256, 0, stream>>>(xW1b, bstart, bcur, binned, b1, h_b);
    k_spmm2f<<<NB, 256, 0, stream>>>(h_b, bstart, bcur, binned, W2f, b2, out);
}

// Round 11
// 197.751 us; speedup vs baseline: 1.5650x; 1.0139x over previous
//
#include <hip/hip_runtime.h>
#include <math.h>

#define N_NODES 50000
#define N_EDGES 800000
#define NFEAT 256
#define NHID 64
#define NCLASS 40
#define NPB 16            // nodes per bucket
#define NB  3125          // 50000 / 16
#define CAP 512           // slots per bucket (mean 256, sigma 16 -> safe)
#define BIN_EPB 8192      // edges per binning block (1024 threads, 8 rounds)
#define NBIN 98           // ceil(800000 / 8192)
#define NGEMM 782         // ceil(50000 / 64)
#define ACC2S 68          // spmm2f acc row stride (pad vs 16-way xpose conflict)

typedef __attribute__((ext_vector_type(8))) short bf16x8;
typedef __attribute__((ext_vector_type(4))) float f32x4;

__device__ __forceinline__ ushort f2bf(float f) {
    unsigned u = __float_as_uint(f);
    u += 0x7FFF + ((u >> 16) & 1);          // round-to-nearest-even
    return (ushort)(u >> 16);
}
__device__ __forceinline__ float bf2f(ushort us) {
    return __uint_as_float(((unsigned)us) << 16);
}

// -------- prep: W1,W2 -> bf16 fragment-ordered tables --------
__global__ __launch_bounds__(256) void k_prep(const float* __restrict__ W1,
                                              const float* __restrict__ W2,
                                              ushort* __restrict__ W1f,
                                              ushort* __restrict__ W2f) {
    int idx = blockIdx.x * 256 + threadIdx.x;
    if (idx < 2048) {                        // W1f: 4 ct * 8 ks * 64 lanes
        int lane = idx & 63, ctks = idx >> 6;
        int ks = ctks & 7, ct = ctks >> 3;
        int col = ct * 16 + (lane & 15);
        int r0 = ks * 32 + (lane >> 4) * 8;
        bf16x8 frag;
        #pragma unroll
        for (int j = 0; j < 8; ++j) frag[j] = (short)f2bf(W1[(r0 + j) * NHID + col]);
        *(bf16x8*)&W1f[(size_t)idx * 8] = frag;
    } else if (idx < 2048 + 384) {           // W2f: 3 ct * 2 ks * 64 lanes
        int i2 = idx - 2048;
        int lane = i2 & 63, ctks = i2 >> 6;
        int ks = ctks & 1, ct = ctks >> 1;
        int col = ct * 16 + (lane & 15);
        int r0 = ks * 32 + (lane >> 4) * 8;
        bf16x8 frag;
        #pragma unroll
        for (int j = 0; j < 8; ++j)
            frag[j] = (short)((col < NCLASS) ? f2bf(W2[(r0 + j) * NCLASS + col]) : 0);
        *(bf16x8*)&W2f[(size_t)i2 * 8] = frag;
    }
}

// -------- mega: blocks 0..NBIN-1 = clustered binning; rest = GEMM1 --------
// Bin: two-phase LDS cluster, ranges claimed from zero-init bfill (capacity CAP).
// Gemm: 64 rows x 64 cols per block, 16 waves (4 row-groups x 4 col-tiles).
__global__ __launch_bounds__(1024) void k_mega(const int* __restrict__ esrc,
                                               const int* __restrict__ edst,
                                               const float* __restrict__ ewt,
                                               int* __restrict__ bfill,
                                               int2* __restrict__ binned,
                                               const float* __restrict__ x,
                                               const ushort* __restrict__ W1f,
                                               ushort* __restrict__ xW1b) {
    __shared__ __align__(16) char smem[64 * 256 * 2];   // 32 KB
    int tid = threadIdx.x;

    if (blockIdx.x < NBIN) {
        // ---------------- binning path ----------------
        int* lcnt  = (int*)smem;             // [NB]
        int* lbase = lcnt + NB;              // [NB]  (25 KB total <= 32 KB)
        for (int i = tid; i < NB; i += 1024) lcnt[i] = 0;
        __syncthreads();
        int base = blockIdx.x * BIN_EPB;
        #pragma unroll
        for (int k = 0; k < BIN_EPB; k += 1024) {
            int e = base + k + tid;
            if (e < N_EDGES) atomicAdd(&lcnt[edst[e] >> 4], 1);
        }
        __syncthreads();
        for (int i = tid; i < NB; i += 1024) {
            int c = lcnt[i];
            lbase[i] = c ? atomicAdd(&bfill[i], c) : 0;
            lcnt[i] = 0;
        }
        __syncthreads();
        #pragma unroll
        for (int k = 0; k < BIN_EPB; k += 1024) {
            int e = base + k + tid;
            if (e < N_EDGES) {
                int d = edst[e];
                int b = d >> 4;
                int pos = b * CAP + lbase[b] + atomicAdd(&lcnt[b], 1);
                binned[pos] = make_int2(esrc[e] | ((d & 15) << 16),
                                        __float_as_int(ewt[e]));
            }
        }
        return;
    }

    // ---------------- GEMM1 path: xW1b = bf16( x @ W1 ) ----------------
    ushort* sX = (ushort*)smem;              // 64 rows x 256 cols bf16
    int w = tid >> 6, lane = tid & 63;
    int ct = w & 3, rg = w >> 2;
    int row0 = (blockIdx.x - NBIN) * 64;

    bf16x8 Bf[8];
    #pragma unroll
    for (int ks = 0; ks < 8; ++ks)
        Bf[ks] = *(const bf16x8*)&W1f[(size_t)((ct * 8 + ks) * 64 + lane) * 8];

    {
        int row = tid & 63;
        int colbase = (tid >> 6) * 16;
        int crow = min(row0 + row, N_NODES - 1);
        const float* xp = x + (size_t)crow * NFEAT + colbase;
        #pragma unroll
        for (int c2 = 0; c2 < 2; ++c2) {
            float4 v0 = *(const float4*)(xp + c2 * 8);
            float4 v1 = *(const float4*)(xp + c2 * 8 + 4);
            bf16x8 fr;
            fr[0] = (short)f2bf(v0.x); fr[1] = (short)f2bf(v0.y);
            fr[2] = (short)f2bf(v0.z); fr[3] = (short)f2bf(v0.w);
            fr[4] = (short)f2bf(v1.x); fr[5] = (short)f2bf(v1.y);
            fr[6] = (short)f2bf(v1.z); fr[7] = (short)f2bf(v1.w);
            int chunk = colbase / 8 + c2;                 // 0..31
            *(bf16x8*)&sX[row * 256 + ((chunk ^ (row & 7)) * 8)] = fr;
        }
    }
    __syncthreads();

    f32x4 acc = {0.f, 0.f, 0.f, 0.f};
    int arow = rg * 16 + (lane & 15);
    #pragma unroll
    for (int ks = 0; ks < 8; ++ks) {
        int chunk = ks * 4 + (lane >> 4);
        bf16x8 Af = *(const bf16x8*)&sX[arow * 256 + ((chunk ^ (arow & 7)) * 8)];
        acc = __builtin_amdgcn_mfma_f32_16x16x32_bf16(Af, Bf[ks], acc, 0, 0, 0);
    }
    int col = ct * 16 + (lane & 15);
    int rbase = row0 + rg * 16 + (lane >> 4) * 4;
    #pragma unroll
    for (int r = 0; r < 4; ++r) {
        int row = rbase + r;
        if (row < N_NODES)
            xW1b[(size_t)row * NHID + col] = f2bf(acc[r]);
    }
}

// ---------------- SPMM1: 4 waves co-process ONE 16-node bucket ----------------
__global__ __launch_bounds__(256) void k_spmm1b(const ushort* __restrict__ xW1b,
                                                const int* __restrict__ bfill,
                                                const int2* __restrict__ binned,
                                                const float* __restrict__ b1,
                                                ushort* __restrict__ h_b) {
    __shared__ float accs[4][NPB * NHID];    // 16 KB
    int wv = threadIdx.x >> 6, lane = threadIdx.x & 63;
    int b = blockIdx.x;
    float* acc = accs[wv];
    #pragma unroll
    for (int n = 0; n < NPB; ++n) acc[n * NHID + lane] = 0.f;

    int s = b * CAP, e = s + bfill[b];
    int len = e - s;
    int q = (len + 3) >> 2;
    int j = s + wv * q;
    int je = min(j + q, e);
    for (; j + 8 <= je; j += 8) {
        int2 p[8];
        #pragma unroll
        for (int k = 0; k < 8; ++k) p[k] = binned[j + k];
        float g[8];
        #pragma unroll
        for (int k = 0; k < 8; ++k)
            g[k] = bf2f(xW1b[(p[k].x & 0xFFFF) * NHID + lane]);
        #pragma unroll
        for (int k = 0; k < 8; ++k)
            acc[(p[k].x >> 16) * NHID + lane] += __int_as_float(p[k].y) * g[k];
    }
    for (; j < je; ++j) {
        int2 p0 = binned[j];
        float g0 = bf2f(xW1b[(p0.x & 0xFFFF) * NHID + lane]);
        acc[(p0.x >> 16) * NHID + lane] += __int_as_float(p0.y) * g0;
    }
    __syncthreads();

    float bias = b1[lane];
    #pragma unroll
    for (int i = 0; i < 4; ++i) {
        int n = wv * 4 + i;
        float v = accs[0][n * NHID + lane] + accs[1][n * NHID + lane]
                + accs[2][n * NHID + lane] + accs[3][n * NHID + lane] + bias;
        h_b[(size_t)(b * NPB + n) * NHID + lane] = f2bf(v > 0.f ? v : 0.f);
    }
}

// ------- SPMM2 fused: (A·h) gathered in f32, then ·W2 via MFMA + softmax -------
__global__ __launch_bounds__(256) void k_spmm2f(const ushort* __restrict__ h_b,
                                                const int* __restrict__ bfill,
                                                const int2* __restrict__ binned,
                                                const ushort* __restrict__ W2f,
                                                const float* __restrict__ b2,
                                                float* __restrict__ out) {
    __shared__ float accs[4][NPB * ACC2S];   // 17 KB
    int wv = threadIdx.x >> 6, lane = threadIdx.x & 63;
    int b = blockIdx.x;
    float* acc = accs[wv];
    #pragma unroll
    for (int n = 0; n < NPB; ++n) acc[n * ACC2S + lane] = 0.f;

    int s = b * CAP, e = s + bfill[b];
    int len = e - s;
    int q = (len + 3) >> 2;
    int j = s + wv * q;
    int je = min(j + q, e);
    for (; j + 8 <= je; j += 8) {
        int2 p[8];
        #pragma unroll
        for (int k = 0; k < 8; ++k) p[k] = binned[j + k];
        float g[8];
        #pragma unroll
        for (int k = 0; k < 8; ++k)
            g[k] = bf2f(h_b[(p[k].x & 0xFFFF) * NHID + lane]);
        #pragma unroll
        for (int k = 0; k < 8; ++k)
            acc[(p[k].x >> 16) * ACC2S + lane] += __int_as_float(p[k].y) * g[k];
    }
    for (; j < je; ++j) {
        int2 p0 = binned[j];
        float g0 = bf2f(h_b[(p0.x & 0xFFFF) * NHID + lane]);
        acc[(p0.x >> 16) * ACC2S + lane] += __int_as_float(p0.y) * g0;
    }
    __syncthreads();

    // reduce 4 slabs -> slab0 (cols 0..63 only)
    for (int i = threadIdx.x; i < NPB * 64; i += 256) {
        int idx = (i >> 6) * ACC2S + (i & 63);
        accs[0][idx] = accs[0][idx] + accs[1][idx] + accs[2][idx] + accs[3][idx];
    }
    __syncthreads();
    if (wv != 0) return;

    // wave 0: A fragments from slab0 (row = lane&15 = node, col = k)
    bf16x8 Af[2];
    #pragma unroll
    for (int ks = 0; ks < 2; ++ks) {
        const float* ap = &accs[0][(lane & 15) * ACC2S + ks * 32 + (lane >> 4) * 8];
        #pragma unroll
        for (int jj = 0; jj < 8; ++jj) Af[ks][jj] = (short)f2bf(ap[jj]);
    }
    f32x4 cv[3] = {{0.f,0.f,0.f,0.f},{0.f,0.f,0.f,0.f},{0.f,0.f,0.f,0.f}};
    #pragma unroll
    for (int ct = 0; ct < 3; ++ct) {
        #pragma unroll
        for (int ks = 0; ks < 2; ++ks) {
            bf16x8 Bf = *(const bf16x8*)&W2f[(size_t)((ct * 2 + ks) * 64 + lane) * 8];
            cv[ct] = __builtin_amdgcn_mfma_f32_16x16x32_bf16(Af[ks], Bf, cv[ct], 0, 0, 0);
        }
    }
    // softmax: lane-group g = lane>>4 owns rows g*4+i; colg = lane&15.
    int colg = lane & 15;
    int g = lane >> 4;
    float bc0 = b2[colg];
    float bc1 = b2[16 + colg];
    float bc2 = (colg < 8) ? b2[32 + colg] : 0.f;
    #pragma unroll
    for (int i = 0; i < 4; ++i) {
        int node = b * NPB + g * 4 + i;
        float v0 = cv[0][i] + bc0;
        float v1 = cv[1][i] + bc1;
        float v2 = (colg < 8) ? (cv[2][i] + bc2) : -INFINITY;
        float m = fmaxf(fmaxf(v0, v1), v2);
        #pragma unroll
        for (int off = 1; off < 16; off <<= 1) m = fmaxf(m, __shfl_xor(m, off));
        float ex = __expf(v0 - m) + __expf(v1 - m) + ((colg < 8) ? __expf(v2 - m) : 0.f);
        #pragma unroll
        for (int off = 1; off < 16; off <<= 1) ex += __shfl_xor(ex, off);
        float ls = __logf(ex) + m;
        float* o0 = out + (size_t)node * NCLASS;
        float* o1 = o0 + (size_t)N_NODES * NCLASS;
        o0[colg] = v0;            o1[colg] = v0 - ls;
        o0[16 + colg] = v1;       o1[16 + colg] = v1 - ls;
        if (colg < 8) { o0[32 + colg] = v2;  o1[32 + colg] = v2 - ls; }
    }
}

// ---------------- launch ----------------

extern "C" void kernel_launch(void* const* d_in, const int* in_sizes, int n_in,
                              void* d_out, int out_size, void* d_ws, size_t ws_size,
                              hipStream_t stream) {
    const float* x    = (const float*)d_in[0];
    const float* W1   = (const float*)d_in[1];
    const float* b1   = (const float*)d_in[2];
    const float* W2   = (const float*)d_in[3];
    const float* b2   = (const float*)d_in[4];
    const float* ewt  = (const float*)d_in[5];
    const int*   esrc = (const int*)d_in[6];
    const int*   edst = (const int*)d_in[7];
    float* out = (float*)d_out;

    // workspace layout (16B-aligned chunks)
    char* p = (char*)d_ws;
    ushort* xW1b = (ushort*)p;   p += (size_t)N_NODES * NHID * 2;      // 6.40 MB
    ushort* h_b  = (ushort*)p;   p += (size_t)N_NODES * NHID * 2;      // 6.40 MB
    int2*   binned = (int2*)p;   p += (size_t)NB * CAP * 8;            // 12.80 MB
    ushort* W1f  = (ushort*)p;   p += 2048 * 8 * 2;                    // 32 KB
    ushort* W2f  = (ushort*)p;   p += 384 * 8 * 2;                     // 6 KB
    int* bfill   = (int*)p;      p += NB * 4;                          // 12.5 KB

    hipMemsetAsync(bfill, 0, NB * sizeof(int), stream);

    k_prep<<<10, 256, 0, stream>>>(W1, W2, W1f, W2f);
    k_mega<<<NBIN + NGEMM, 1024, 0, stream>>>(esrc, edst, ewt, bfill, binned,
                                              x, W1f, xW1b);
    k_spmm1b<<<NB, 256, 0, stream>>>(xW1b, bfill, binned, b1, h_b);
    k_spmm2f<<<NB, 256, 0, stream>>>(h_b, bfill, binned, W2f, b2, out);
}

// Round 12
// 189.357 us; speedup vs baseline: 1.6344x; 1.0443x over previous
//
#include <hip/hip_runtime.h>
#include <math.h>

#define N_NODES 50000
#define N_EDGES 800000
#define NFEAT 256
#define NHID 64
#define NCLASS 40
#define NPB 16            // nodes per fine bucket
#define NB  3125          // fine buckets = 50000 / 16
#define CAP 512           // slots per fine bucket (mean 256, sigma 16)
#define NC 98             // coarse buckets: dst>>9 (512 nodes each)
#define CAPC 16384        // slots per coarse bucket (mean 8163, sigma 90)
#define BIN_EPB 8192      // edges per pass-A block
#define NBIN 98           // ceil(800000 / 8192)
#define NGEMM 782         // ceil(50000 / 64)
#define ACC2S 68          // spmm2f acc row stride

typedef __attribute__((ext_vector_type(8))) short bf16x8;
typedef __attribute__((ext_vector_type(4))) float f32x4;

__device__ __forceinline__ ushort f2bf(float f) {
    unsigned u = __float_as_uint(f);
    u += 0x7FFF + ((u >> 16) & 1);          // round-to-nearest-even
    return (ushort)(u >> 16);
}
__device__ __forceinline__ float bf2f(ushort us) {
    return __uint_as_float(((unsigned)us) << 16);
}

// -------- prep: W1,W2 -> bf16 fragment-ordered tables --------
__global__ __launch_bounds__(256) void k_prep(const float* __restrict__ W1,
                                              const float* __restrict__ W2,
                                              ushort* __restrict__ W1f,
                                              ushort* __restrict__ W2f) {
    int idx = blockIdx.x * 256 + threadIdx.x;
    if (idx < 2048) {                        // W1f: 4 ct * 8 ks * 64 lanes
        int lane = idx & 63, ctks = idx >> 6;
        int ks = ctks & 7, ct = ctks >> 3;
        int col = ct * 16 + (lane & 15);
        int r0 = ks * 32 + (lane >> 4) * 8;
        bf16x8 frag;
        #pragma unroll
        for (int j = 0; j < 8; ++j) frag[j] = (short)f2bf(W1[(r0 + j) * NHID + col]);
        *(bf16x8*)&W1f[(size_t)idx * 8] = frag;
    } else if (idx < 2048 + 384) {           // W2f: 3 ct * 2 ks * 64 lanes
        int i2 = idx - 2048;
        int lane = i2 & 63, ctks = i2 >> 6;
        int ks = ctks & 1, ct = ctks >> 1;
        int col = ct * 16 + (lane & 15);
        int r0 = ks * 32 + (lane >> 4) * 8;
        bf16x8 frag;
        #pragma unroll
        for (int j = 0; j < 8; ++j)
            frag[j] = (short)((col < NCLASS) ? f2bf(W2[(r0 + j) * NCLASS + col]) : 0);
        *(bf16x8*)&W2f[(size_t)i2 * 8] = frag;
    }
}

// -------- mega: blocks 0..NBIN-1 = COARSE binning; rest = GEMM1 --------
// Coarse bin: runs of ~84 edges (672B) per claim -> near-full-line writes.
// Payload: x = src(16b) | dstlow9(9b)<<16, y = weight bits.
__global__ __launch_bounds__(1024) void k_mega(const int* __restrict__ esrc,
                                               const int* __restrict__ edst,
                                               const float* __restrict__ ewt,
                                               int* __restrict__ bfillc,
                                               int2* __restrict__ coarse,
                                               const float* __restrict__ x,
                                               const ushort* __restrict__ W1f,
                                               ushort* __restrict__ xW1b) {
    __shared__ __align__(16) char smem[64 * 256 * 2];   // 32 KB
    int tid = threadIdx.x;

    if (blockIdx.x < NBIN) {
        // ---------------- coarse binning ----------------
        int* cnt  = (int*)smem;              // [NC]
        int* base = cnt + NC;                // [NC]
        for (int i = tid; i < NC; i += 1024) cnt[i] = 0;
        __syncthreads();
        int eb = blockIdx.x * BIN_EPB;
        #pragma unroll
        for (int k = 0; k < BIN_EPB; k += 1024) {
            int e = eb + k + tid;
            if (e < N_EDGES) atomicAdd(&cnt[edst[e] >> 9], 1);
        }
        __syncthreads();
        for (int i = tid; i < NC; i += 1024) {
            int c = cnt[i];
            base[i] = c ? atomicAdd(&bfillc[i], c) : 0;
            cnt[i] = 0;
        }
        __syncthreads();
        #pragma unroll
        for (int k = 0; k < BIN_EPB; k += 1024) {
            int e = eb + k + tid;
            if (e < N_EDGES) {
                int d = edst[e];
                int c = d >> 9;
                int pos = base[c] + atomicAdd(&cnt[c], 1);
                coarse[(size_t)c * CAPC + pos] =
                    make_int2(esrc[e] | ((d & 511) << 16), __float_as_int(ewt[e]));
            }
        }
        return;
    }

    // ---------------- GEMM1 path: xW1b = bf16( x @ W1 ) ----------------
    ushort* sX = (ushort*)smem;              // 64 rows x 256 cols bf16
    int w = tid >> 6, lane = tid & 63;
    int ct = w & 3, rg = w >> 2;
    int row0 = (blockIdx.x - NBIN) * 64;

    bf16x8 Bf[8];
    #pragma unroll
    for (int ks = 0; ks < 8; ++ks)
        Bf[ks] = *(const bf16x8*)&W1f[(size_t)((ct * 8 + ks) * 64 + lane) * 8];

    {
        int row = tid & 63;
        int colbase = (tid >> 6) * 16;
        int crow = min(row0 + row, N_NODES - 1);
        const float* xp = x + (size_t)crow * NFEAT + colbase;
        #pragma unroll
        for (int c2 = 0; c2 < 2; ++c2) {
            float4 v0 = *(const float4*)(xp + c2 * 8);
            float4 v1 = *(const float4*)(xp + c2 * 8 + 4);
            bf16x8 fr;
            fr[0] = (short)f2bf(v0.x); fr[1] = (short)f2bf(v0.y);
            fr[2] = (short)f2bf(v0.z); fr[3] = (short)f2bf(v0.w);
            fr[4] = (short)f2bf(v1.x); fr[5] = (short)f2bf(v1.y);
            fr[6] = (short)f2bf(v1.z); fr[7] = (short)f2bf(v1.w);
            int chunk = colbase / 8 + c2;                 // 0..31
            *(bf16x8*)&sX[row * 256 + ((chunk ^ (row & 7)) * 8)] = fr;
        }
    }
    __syncthreads();

    f32x4 acc = {0.f, 0.f, 0.f, 0.f};
    int arow = rg * 16 + (lane & 15);
    #pragma unroll
    for (int ks = 0; ks < 8; ++ks) {
        int chunk = ks * 4 + (lane >> 4);
        bf16x8 Af = *(const bf16x8*)&sX[arow * 256 + ((chunk ^ (arow & 7)) * 8)];
        acc = __builtin_amdgcn_mfma_f32_16x16x32_bf16(Af, Bf[ks], acc, 0, 0, 0);
    }
    int col = ct * 16 + (lane & 15);
    int rbase = row0 + rg * 16 + (lane >> 4) * 4;
    #pragma unroll
    for (int r = 0; r < 4; ++r) {
        int row = rbase + r;
        if (row < N_NODES)
            xW1b[(size_t)row * NHID + col] = f2bf(acc[r]);
    }
}

// -------- pass B: coarse -> fine (32 buckets per coarse, full-line runs) --------
// 2 blocks per coarse bucket; runs ~128 edges (1KB). Final format = binned[fb*CAP].
__global__ __launch_bounds__(512) void k_passB(const int* __restrict__ bfillc,
                                               const int2* __restrict__ coarse,
                                               int* __restrict__ bfill,
                                               int2* __restrict__ binned) {
    __shared__ int cnt[32];
    __shared__ int base[32];
    int tid = threadIdx.x;
    int c = blockIdx.x >> 1;
    int half = blockIdx.x & 1;
    int fillc = bfillc[c];
    int h0 = (fillc + 1) >> 1;
    int js = c * CAPC + half * h0;
    int je = c * CAPC + (half ? fillc : h0);

    if (tid < 32) cnt[tid] = 0;
    __syncthreads();
    for (int j = js + tid; j < je; j += 512) {
        int dstlow = (coarse[j].x >> 16) & 511;
        atomicAdd(&cnt[dstlow >> 4], 1);
    }
    __syncthreads();
    if (tid < 32) {
        int cc = cnt[tid];
        base[tid] = cc ? atomicAdd(&bfill[c * 32 + tid], cc) : 0;
        cnt[tid] = 0;
    }
    __syncthreads();
    for (int j = js + tid; j < je; j += 512) {
        int2 p = coarse[j];
        int dstlow = (p.x >> 16) & 511;
        int fb = dstlow >> 4;
        int pos = base[fb] + atomicAdd(&cnt[fb], 1);
        binned[(size_t)(c * 32 + fb) * CAP + pos] =
            make_int2((p.x & 0xFFFF) | ((dstlow & 15) << 16), p.y);
    }
}

// ---------------- SPMM1: 4 waves co-process ONE 16-node bucket ----------------
__global__ __launch_bounds__(256) void k_spmm1b(const ushort* __restrict__ xW1b,
                                                const int* __restrict__ bfill,
                                                const int2* __restrict__ binned,
                                                const float* __restrict__ b1,
                                                ushort* __restrict__ h_b) {
    __shared__ float accs[4][NPB * NHID];    // 16 KB
    int wv = threadIdx.x >> 6, lane = threadIdx.x & 63;
    int b = blockIdx.x;
    float* acc = accs[wv];
    #pragma unroll
    for (int n = 0; n < NPB; ++n) acc[n * NHID + lane] = 0.f;

    int s = b * CAP, e = s + bfill[b];
    int len = e - s;
    int q = (len + 3) >> 2;
    int j = s + wv * q;
    int je = min(j + q, e);
    for (; j + 8 <= je; j += 8) {
        int2 p[8];
        #pragma unroll
        for (int k = 0; k < 8; ++k) p[k] = binned[j + k];
        float g[8];
        #pragma unroll
        for (int k = 0; k < 8; ++k)
            g[k] = bf2f(xW1b[(p[k].x & 0xFFFF) * NHID + lane]);
        #pragma unroll
        for (int k = 0; k < 8; ++k)
            acc[(p[k].x >> 16) * NHID + lane] += __int_as_float(p[k].y) * g[k];
    }
    for (; j < je; ++j) {
        int2 p0 = binned[j];
        float g0 = bf2f(xW1b[(p0.x & 0xFFFF) * NHID + lane]);
        acc[(p0.x >> 16) * NHID + lane] += __int_as_float(p0.y) * g0;
    }
    __syncthreads();

    float bias = b1[lane];
    #pragma unroll
    for (int i = 0; i < 4; ++i) {
        int n = wv * 4 + i;
        float v = accs[0][n * NHID + lane] + accs[1][n * NHID + lane]
                + accs[2][n * NHID + lane] + accs[3][n * NHID + lane] + bias;
        h_b[(size_t)(b * NPB + n) * NHID + lane] = f2bf(v > 0.f ? v : 0.f);
    }
}

// ------- SPMM2 fused: (A·h) gathered in f32, then ·W2 via MFMA + softmax -------
__global__ __launch_bounds__(256) void k_spmm2f(const ushort* __restrict__ h_b,
                                                const int* __restrict__ bfill,
                                                const int2* __restrict__ binned,
                                                const ushort* __restrict__ W2f,
                                                const float* __restrict__ b2,
                                                float* __restrict__ out) {
    __shared__ float accs[4][NPB * ACC2S];   // 17 KB
    int wv = threadIdx.x >> 6, lane = threadIdx.x & 63;
    int b = blockIdx.x;
    float* acc = accs[wv];
    #pragma unroll
    for (int n = 0; n < NPB; ++n) acc[n * ACC2S + lane] = 0.f;

    int s = b * CAP, e = s + bfill[b];
    int len = e - s;
    int q = (len + 3) >> 2;
    int j = s + wv * q;
    int je = min(j + q, e);
    for (; j + 8 <= je; j += 8) {
        int2 p[8];
        #pragma unroll
        for (int k = 0; k < 8; ++k) p[k] = binned[j + k];
        float g[8];
        #pragma unroll
        for (int k = 0; k < 8; ++k)
            g[k] = bf2f(h_b[(p[k].x & 0xFFFF) * NHID + lane]);
        #pragma unroll
        for (int k = 0; k < 8; ++k)
            acc[(p[k].x >> 16) * ACC2S + lane] += __int_as_float(p[k].y) * g[k];
    }
    for (; j < je; ++j) {
        int2 p0 = binned[j];
        float g0 = bf2f(h_b[(p0.x & 0xFFFF) * NHID + lane]);
        acc[(p0.x >> 16) * ACC2S + lane] += __int_as_float(p0.y) * g0;
    }
    __syncthreads();

    // reduce 4 slabs -> slab0 (cols 0..63 only)
    for (int i = threadIdx.x; i < NPB * 64; i += 256) {
        int idx = (i >> 6) * ACC2S + (i & 63);
        accs[0][idx] = accs[0][idx] + accs[1][idx] + accs[2][idx] + accs[3][idx];
    }
    __syncthreads();
    if (wv != 0) return;

    // wave 0: A fragments from slab0 (row = lane&15 = node, col = k)
    bf16x8 Af[2];
    #pragma unroll
    for (int ks = 0; ks < 2; ++ks) {
        const float* ap = &accs[0][(lane & 15) * ACC2S + ks * 32 + (lane >> 4) * 8];
        #pragma unroll
        for (int jj = 0; jj < 8; ++jj) Af[ks][jj] = (short)f2bf(ap[jj]);
    }
    f32x4 cv[3] = {{0.f,0.f,0.f,0.f},{0.f,0.f,0.f,0.f},{0.f,0.f,0.f,0.f}};
    #pragma unroll
    for (int ct = 0; ct < 3; ++ct) {
        #pragma unroll
        for (int ks = 0; ks < 2; ++ks) {
            bf16x8 Bf = *(const bf16x8*)&W2f[(size_t)((ct * 2 + ks) * 64 + lane) * 8];
            cv[ct] = __builtin_amdgcn_mfma_f32_16x16x32_bf16(Af[ks], Bf, cv[ct], 0, 0, 0);
        }
    }
    // softmax: lane-group g = lane>>4 owns rows g*4+i; colg = lane&15.
    int colg = lane & 15;
    int g = lane >> 4;
    float bc0 = b2[colg];
    float bc1 = b2[16 + colg];
    float bc2 = (colg < 8) ? b2[32 + colg] : 0.f;
    #pragma unroll
    for (int i = 0; i < 4; ++i) {
        int node = b * NPB + g * 4 + i;
        float v0 = cv[0][i] + bc0;
        float v1 = cv[1][i] + bc1;
        float v2 = (colg < 8) ? (cv[2][i] + bc2) : -INFINITY;
        float m = fmaxf(fmaxf(v0, v1), v2);
        #pragma unroll
        for (int off = 1; off < 16; off <<= 1) m = fmaxf(m, __shfl_xor(m, off));
        float ex = __expf(v0 - m) + __expf(v1 - m) + ((colg < 8) ? __expf(v2 - m) : 0.f);
        #pragma unroll
        for (int off = 1; off < 16; off <<= 1) ex += __shfl_xor(ex, off);
        float ls = __logf(ex) + m;
        float* o0 = out + (size_t)node * NCLASS;
        float* o1 = o0 + (size_t)N_NODES * NCLASS;
        o0[colg] = v0;            o1[colg] = v0 - ls;
        o0[16 + colg] = v1;       o1[16 + colg] = v1 - ls;
        if (colg < 8) { o0[32 + colg] = v2;  o1[32 + colg] = v2 - ls; }
    }
}

// ---------------- launch ----------------

extern "C" void kernel_launch(void* const* d_in, const int* in_sizes, int n_in,
                              void* d_out, int out_size, void* d_ws, size_t ws_size,
                              hipStream_t stream) {
    const float* x    = (const float*)d_in[0];
    const float* W1   = (const float*)d_in[1];
    const float* b1   = (const float*)d_in[2];
    const float* W2   = (const float*)d_in[3];
    const float* b2   = (const float*)d_in[4];
    const float* ewt  = (const float*)d_in[5];
    const int*   esrc = (const int*)d_in[6];
    const int*   edst = (const int*)d_in[7];
    float* out = (float*)d_out;

    // workspace layout (16B-aligned chunks)
    char* p = (char*)d_ws;
    ushort* xW1b = (ushort*)p;   p += (size_t)N_NODES * NHID * 2;      // 6.40 MB
    ushort* h_b  = (ushort*)p;   p += (size_t)N_NODES * NHID * 2;      // 6.40 MB
    int2*   binned = (int2*)p;   p += (size_t)NB * CAP * 8 + 64;       // 12.80 MB
    int2*   coarse = (int2*)p;   p += (size_t)NC * CAPC * 8;           // 12.85 MB
    ushort* W1f  = (ushort*)p;   p += 2048 * 8 * 2;                    // 32 KB
    ushort* W2f  = (ushort*)p;   p += 384 * 8 * 2;                     // 6 KB
    int* bfillc  = (int*)p;      p += NC * 4;                          // coarse fills
    int* bfill   = (int*)p;      p += NB * 4;                          // fine fills

    hipMemsetAsync(bfillc, 0, (NC + NB) * sizeof(int), stream);

    k_prep<<<10, 256, 0, stream>>>(W1, W2, W1f, W2f);
    k_mega<<<NBIN + NGEMM, 1024, 0, stream>>>(esrc, edst, ewt, bfillc, coarse,
                                              x, W1f, xW1b);
    k_passB<<<NC * 2, 512, 0, stream>>>(bfillc, coarse, bfill, binned);
    k_spmm1b<<<NB, 256, 0, stream>>>(xW1b, bfill, binned, b1, h_b);
    k_spmm2f<<<NB, 256, 0, stream>>>(h_b, bfill, binned, W2f, b2, out);
}